// Round 1
// baseline (3736.117 us; speedup 1.0000x reference)
//
#include <hip/hip_runtime.h>
#include <cstdint>
#include <cstddef>

// Problem constants
#define W_IMG 128
#define HW    16384            // 128*128
#define T_STEPS 20
#define BATCH 8
#define Y_SIZE 2621440         // 20*8*16384
#define HS_SLICE 1048576       // 8*8*16384  (one [t,s] slice)

__device__ __forceinline__ float sigm(float x) { return 1.0f / (1.0f + __expf(-x)); }
// tanh(x) = 1 - 2/(exp(2x)+1); safe at +/-inf, no NaN
__device__ __forceinline__ float tanh_fast(float x) { return 1.0f - 2.0f / (__expf(2.0f * x) + 1.0f); }

// ---------------------------------------------------------------------------
// Weight transpose: orig [oc][ic][3][3]  ->  wT [ic][ky][kx][oc(8)]
// so the inner conv loops can fetch 8-oc octets with wave-uniform s_loads.
// wT lives in the hs[19,3] slice of d_out (written before use, zeroed last).
// ---------------------------------------------------------------------------
struct PrepArgs {
    const float* w[12];
    float* wT;
};

__global__ __launch_bounds__(256) void prep_kernel(PrepArgs a) {
    const int IC[12]  = {9, 9, 9, 16, 16, 16, 16, 16, 16, 8, 8, 8};
    const int OCc[12] = {8, 8, 8, 8, 8, 8, 8, 8, 8, 8, 8, 1};
    const int OFF[12] = {0, 648, 1296, 1944, 3096, 4248, 5400, 6552, 7704, 8856, 9432, 10008};
    const int c = blockIdx.x;           // one conv per block (grid = 12)
    const int n = IC[c] * 72;           // ic*9 taps * 8 oc (oc padded to 8)
    const float* ws = a.w[c];
    float* wd = a.wT + OFF[c];
    for (int i = threadIdx.x; i < n; i += 256) {
        const int o = i & 7;
        const int rest = i >> 3;                 // ic*9 + tap
        const int ic = rest / 9, tap = rest - ic * 9;
        float v = 0.0f;
        if (o < OCc[c]) v = ws[(o * IC[c] + ic) * 9 + tap];
        wd[i] = v;                               // dest index == (ic*9+tap)*8 + o == i
    }
}

// ---------------------------------------------------------------------------
// Fused GRU cell for one 32x32 tile.
// Phase 1: r = sigmoid(conv([x,h], wr)+br) on the (32+2D)^2 halo region;
//          store r*h into LDS.
// Phase 2: z-conv + candidate-conv (rh from LDS, x from global), GRU update,
//          write h_new straight into the hs output slice.
// ---------------------------------------------------------------------------
template <int D, int XN>
__device__ void gru_unit(const float* __restrict__ xb, const float* __restrict__ hprev,
                         float* __restrict__ outp,
                         const float* __restrict__ wTz, const float* __restrict__ wTr,
                         const float* __restrict__ wTh,
                         const float* __restrict__ bz, const float* __restrict__ br,
                         const float* __restrict__ bh,
                         int y0, int x0, float* smem) {
    constexpr int E  = 32 + 2 * D;   // extended (rh) region side
    constexpr int IC = XN + 8;       // input channels of z/r convs
    constexpr int SW = 4 + 2 * D;    // strip width for 4-px groups
    const int tid = threadIdx.x;

    // ---------------- phase 1: rh on extended region ----------------
    float brv[8];
#pragma unroll
    for (int o = 0; o < 8; o++) brv[o] = br[o];

    for (int i = tid; i < E * E; i += 256) {
        const int ey = i / E, ex = i - ey * E;
        const int gy = y0 - D + ey, gx = x0 - D + ex;
        float acc[8];
#pragma unroll
        for (int o = 0; o < 8; o++) acc[o] = 0.0f;
        for (int ic = 0; ic < IC; ic++) {
            const float* src;
            if (ic < XN) {
                src = xb + ic * HW;
            } else {
                if (!hprev) break;               // h == 0 at t=0: no contribution
                src = hprev + (ic - XN) * HW;
            }
            const float* wic = wTr + ic * 72;
#pragma unroll
            for (int ky = 0; ky < 3; ky++) {
                const int yy = gy + (ky - 1) * D;
                const bool rok = (unsigned)yy < 128u;
                const float* row = src + yy * W_IMG;
#pragma unroll
                for (int kx = 0; kx < 3; kx++) {
                    const int xx = gx + (kx - 1) * D;
                    const float v = (rok & ((unsigned)xx < 128u)) ? row[xx] : 0.0f;
                    const float* w8 = wic + (ky * 3 + kx) * 8;
#pragma unroll
                    for (int o = 0; o < 8; o++) acc[o] = fmaf(w8[o], v, acc[o]);
                }
            }
        }
        const bool inimg = ((unsigned)gy < 128u) & ((unsigned)gx < 128u);
#pragma unroll
        for (int o = 0; o < 8; o++) {
            const float r = sigm(acc[o] + brv[o]);
            const float hv = (hprev && inimg) ? hprev[o * HW + gy * W_IMG + gx] : 0.0f;
            smem[(o * E + ey) * E + ex] = r * hv;   // 0 outside image (h pads with 0)
        }
    }
    __syncthreads();

    // ---------------- phase 2: z conv + candidate conv + update ----------------
    const int ry  = tid >> 3;           // 0..31 tile row
    const int cx0 = (tid & 7) << 2;     // 4-px column group
    const int gy  = y0 + ry;
    const int gx0 = x0 + cx0;

    float az[8][4], ah[8][4];
#pragma unroll
    for (int o = 0; o < 8; o++)
#pragma unroll
        for (int p = 0; p < 4; p++) { az[o][p] = 0.0f; ah[o][p] = 0.0f; }

    const int ICeff = hprev ? IC : XN;
    for (int ic = 0; ic < ICeff; ic++) {
        const float* src  = (ic < XN) ? (xb + ic * HW) : (hprev + (ic - XN) * HW);
        const float* wzic = wTz + ic * 72;
        const float* whic = wTh + (8 + ic) * 72;   // only dereferenced when ic < XN
#pragma unroll
        for (int ky = 0; ky < 3; ky++) {
            const int yy = gy + (ky - 1) * D;
            const bool rok = (unsigned)yy < 128u;
            const float* row = src + yy * W_IMG;
            float v[SW];
#pragma unroll
            for (int j = 0; j < SW; j++) {
                const int xx = gx0 - D + j;
                v[j] = (rok & ((unsigned)xx < 128u)) ? row[xx] : 0.0f;
            }
#pragma unroll
            for (int kx = 0; kx < 3; kx++) {
                const float* w8 = wzic + (ky * 3 + kx) * 8;
#pragma unroll
                for (int o = 0; o < 8; o++) {
                    const float wv = w8[o];
#pragma unroll
                    for (int p = 0; p < 4; p++) az[o][p] = fmaf(wv, v[kx * D + p], az[o][p]);
                }
                if (ic < XN) {   // candidate conv: x part (channels 8+ic of wh)
                    const float* w8h = whic + (ky * 3 + kx) * 8;
#pragma unroll
                    for (int o = 0; o < 8; o++) {
                        const float wv = w8h[o];
#pragma unroll
                        for (int p = 0; p < 4; p++) ah[o][p] = fmaf(wv, v[kx * D + p], ah[o][p]);
                    }
                }
            }
        }
    }

    // candidate conv: rh part from LDS (channels 0..7 of wh)
    for (int ic = 0; ic < 8; ic++) {
        const float* whic = wTh + ic * 72;
#pragma unroll
        for (int ky = 0; ky < 3; ky++) {
            const int ey = ry + ky * D;
            const float* srow = smem + (ic * E + ey) * E + cx0;
            float v[SW];
#pragma unroll
            for (int j = 0; j < SW; j++) v[j] = srow[j];
#pragma unroll
            for (int kx = 0; kx < 3; kx++) {
                const float* w8 = whic + (ky * 3 + kx) * 8;
#pragma unroll
                for (int o = 0; o < 8; o++) {
                    const float wv = w8[o];
#pragma unroll
                    for (int p = 0; p < 4; p++) ah[o][p] = fmaf(wv, v[kx * D + p], ah[o][p]);
                }
            }
        }
    }

    // epilogue: h_new = (1-z)*h + z*tanh(...)
#pragma unroll
    for (int o = 0; o < 8; o++) {
        const float bzv = bz[o], bhv = bh[o];
        const float* hp = hprev ? (hprev + o * HW + gy * W_IMG + gx0) : nullptr;
        float* op = outp + o * HW + gy * W_IMG + gx0;
        float res[4];
#pragma unroll
        for (int p = 0; p < 4; p++) {
            const float z  = sigm(az[o][p] + bzv);
            const float hc = tanh_fast(ah[o][p] + bhv);
            const float hv = hp ? hp[p] : 0.0f;
            res[p] = (1.0f - z) * hv + z * hc;
        }
        *(float4*)op = make_float4(res[0], res[1], res[2], res[3]);
    }
}

// ---------------------------------------------------------------------------
// Wave kernel: diagonal pipeline. At wave w: layer0@t=w, layer1@t=w-1,
// layer2@t=w-2 run concurrently (128 blocks each). h state lives in hs.
// ---------------------------------------------------------------------------
struct WaveArgs {
    const float* X;
    float* hs;
    const float* wT;
    const float* bz[3];
    const float* br[3];
    const float* bh[3];
    int w;
};

__global__ __launch_bounds__(256) void wave_kernel(WaveArgs a) {
    __shared__ float smem[12800];      // 8 * 40 * 40 (max rh region, d=4)
    const int unit = blockIdx.x >> 7;
    const int t = a.w - unit;
    if (t < 0 || t >= T_STEPS) return;
    const int tile = blockIdx.x & 127;
    const int b = tile >> 4;
    const int ty = (tile >> 2) & 3, tx = tile & 3;
    const int y0 = ty * 32, x0 = tx * 32;
    float* hs = a.hs;
    const float* hprev = (t == 0) ? nullptr
                         : hs + (size_t)(((t - 1) * 4 + unit) * 8 + b) * (8 * HW);
    float* outp = hs + (size_t)((t * 4 + unit) * 8 + b) * (8 * HW);

    if (unit == 0) {
        const float* xb = a.X + (size_t)(t * 8 + b) * HW;
        gru_unit<1, 1>(xb, hprev, outp, a.wT + 0, a.wT + 648, a.wT + 1296,
                       a.bz[0], a.br[0], a.bh[0], y0, x0, smem);
    } else if (unit == 1) {
        const float* xb = hs + (size_t)((t * 4 + 0) * 8 + b) * (8 * HW);
        gru_unit<2, 8>(xb, hprev, outp, a.wT + 1944, a.wT + 3096, a.wT + 4248,
                       a.bz[1], a.br[1], a.bh[1], y0, x0, smem);
    } else {
        const float* xb = hs + (size_t)((t * 4 + 1) * 8 + b) * (8 * HW);
        gru_unit<4, 8>(xb, hprev, outp, a.wT + 5400, a.wT + 6552, a.wT + 7704,
                       a.bz[2], a.br[2], a.bh[2], y0, x0, smem);
    }
}

// ---------------------------------------------------------------------------
// Head: y = sigmoid(conv1(relu(conv1(relu(conv2(h2)))))) fused per 32x16 tile,
// batched over all (t,b). LDS chain: h2[8][24][40] -> y1[8][20][36] ->
// y2[8][18][34] -> y[16][32].
// ---------------------------------------------------------------------------
struct HeadArgs {
    const float* hs;
    const float* wT;
    float* y;
    const float* bo1;
    const float* bo2;
    const float* bo;
};

__global__ __launch_bounds__(256) void head_kernel(HeadArgs a) {
    __shared__ float bufA[7680];   // h2 ext [8][24][40], later y2 [8][18][34]
    __shared__ float bufB[5760];   // y1 [8][20][36]
    const int tid = threadIdx.x;
    const int img = blockIdx.x >> 5;        // t*8 + b
    const int tile = blockIdx.x & 31;
    const int tx = tile & 3, tyy = tile >> 2;
    const int y0 = tyy * 16, x0 = tx * 32;
    const int t = img >> 3, b = img & 7;
    const float* h2 = a.hs + (size_t)((t * 4 + 2) * 8 + b) * (8 * HW);

    // P0: load h2 ext tile (zero-padded)
    for (int i = tid; i < 7680; i += 256) {
        const int c = i / 960, rem = i - c * 960;
        const int ey = rem / 40, ex = rem - ey * 40;
        const int gy = y0 - 4 + ey, gx = x0 - 4 + ex;
        float v = 0.0f;
        if (((unsigned)gy < 128u) && ((unsigned)gx < 128u)) v = h2[c * HW + gy * W_IMG + gx];
        bufA[i] = v;
    }
    __syncthreads();

    // P1: y1 = relu(conv d=2) on [8][20][36]
    {
        const float* wc = a.wT + 8856;
        float b1[8];
#pragma unroll
        for (int o = 0; o < 8; o++) b1[o] = a.bo1[o];
        for (int i = tid; i < 720; i += 256) {
            const int ey = i / 36, ex = i - ey * 36;
            const int gy = y0 - 2 + ey, gx = x0 - 2 + ex;
            const bool inb = ((unsigned)gy < 128u) & ((unsigned)gx < 128u);
            float acc[8];
#pragma unroll
            for (int o = 0; o < 8; o++) acc[o] = 0.0f;
            if (inb) {
                for (int ic = 0; ic < 8; ic++) {
#pragma unroll
                    for (int ky = 0; ky < 3; ky++) {
#pragma unroll
                        for (int kx = 0; kx < 3; kx++) {
                            const float v = bufA[(ic * 24 + ey + 2 + (ky - 1) * 2) * 40 + ex + 2 + (kx - 1) * 2];
                            const float* w8 = wc + ((ic * 3 + ky) * 3 + kx) * 8;
#pragma unroll
                            for (int o = 0; o < 8; o++) acc[o] = fmaf(w8[o], v, acc[o]);
                        }
                    }
                }
            }
#pragma unroll
            for (int o = 0; o < 8; o++)
                bufB[(o * 20 + ey) * 36 + ex] = inb ? fmaxf(acc[o] + b1[o], 0.0f) : 0.0f;
        }
    }
    __syncthreads();

    // P2: y2 = relu(conv d=1) on [8][18][34] -> bufA
    {
        const float* wc = a.wT + 9432;
        float b2[8];
#pragma unroll
        for (int o = 0; o < 8; o++) b2[o] = a.bo2[o];
        for (int i = tid; i < 612; i += 256) {
            const int ey = i / 34, ex = i - ey * 34;
            const int gy = y0 - 1 + ey, gx = x0 - 1 + ex;
            const bool inb = ((unsigned)gy < 128u) & ((unsigned)gx < 128u);
            float acc[8];
#pragma unroll
            for (int o = 0; o < 8; o++) acc[o] = 0.0f;
            if (inb) {
                for (int ic = 0; ic < 8; ic++) {
#pragma unroll
                    for (int ky = 0; ky < 3; ky++) {
#pragma unroll
                        for (int kx = 0; kx < 3; kx++) {
                            const float v = bufB[(ic * 20 + ey + 1 + (ky - 1)) * 36 + ex + 1 + (kx - 1)];
                            const float* w8 = wc + ((ic * 3 + ky) * 3 + kx) * 8;
#pragma unroll
                            for (int o = 0; o < 8; o++) acc[o] = fmaf(w8[o], v, acc[o]);
                        }
                    }
                }
            }
#pragma unroll
            for (int o = 0; o < 8; o++)
                bufA[(o * 18 + ey) * 34 + ex] = inb ? fmaxf(acc[o] + b2[o], 0.0f) : 0.0f;
        }
    }
    __syncthreads();

    // P3: y = sigmoid(conv d=1, 8->1) on [16][32]
    {
        const float* wc = a.wT + 10008;
        const float bo0 = a.bo[0];
        for (int i = tid; i < 512; i += 256) {
            const int ry = i >> 5, cx = i & 31;
            float acc = 0.0f;
            for (int ic = 0; ic < 8; ic++) {
#pragma unroll
                for (int ky = 0; ky < 3; ky++) {
#pragma unroll
                    for (int kx = 0; kx < 3; kx++) {
                        const float v = bufA[(ic * 18 + ry + 1 + (ky - 1)) * 34 + cx + 1 + (kx - 1)];
                        acc = fmaf(wc[((ic * 3 + ky) * 3 + kx) * 8], v, acc);
                    }
                }
            }
            a.y[(size_t)img * HW + (y0 + ry) * W_IMG + x0 + cx] = sigm(acc + bo0);
        }
    }
}

// ---------------------------------------------------------------------------
// Zero-fill hs[:,3] (including the slice that temporarily held wT).
// ---------------------------------------------------------------------------
__global__ __launch_bounds__(256) void zero_kernel(float* hs) {
    const size_t i = (size_t)blockIdx.x * 256 + threadIdx.x;  // < 1310720
#pragma unroll
    for (int k = 0; k < 4; k++) {
        const size_t idx = i + (size_t)k * 1310720;  // float4 index < 5242880
        const size_t t = idx >> 18;                   // / 262144
        const size_t rem = idx & 262143;
        float4* p = (float4*)(hs + (t * 4 + 3) * (size_t)HS_SLICE);
        p[rem] = make_float4(0.0f, 0.0f, 0.0f, 0.0f);
    }
}

// ---------------------------------------------------------------------------
extern "C" void kernel_launch(void* const* d_in, const int* in_sizes, int n_in,
                              void* d_out, int out_size, void* d_ws, size_t ws_size,
                              hipStream_t stream) {
    (void)in_sizes; (void)n_in; (void)d_ws; (void)ws_size; (void)out_size;

    const float* X = (const float*)d_in[0];
    float* y  = (float*)d_out;
    float* hs = (float*)d_out + Y_SIZE;
    float* wT = hs + (size_t)79 * HS_SLICE;   // hs[19,3] slice as weight scratch

    PrepArgs pa;
    pa.w[0]  = (const float*)d_in[1];   // w1z
    pa.w[1]  = (const float*)d_in[3];   // w1r
    pa.w[2]  = (const float*)d_in[5];   // w1h
    pa.w[3]  = (const float*)d_in[7];   // w2z
    pa.w[4]  = (const float*)d_in[9];   // w2r
    pa.w[5]  = (const float*)d_in[11];  // w2h
    pa.w[6]  = (const float*)d_in[13];  // w3z
    pa.w[7]  = (const float*)d_in[15];  // w3r
    pa.w[8]  = (const float*)d_in[17];  // w3h
    pa.w[9]  = (const float*)d_in[19];  // wo1
    pa.w[10] = (const float*)d_in[21];  // wo2
    pa.w[11] = (const float*)d_in[23];  // wo
    pa.wT = wT;
    prep_kernel<<<dim3(12), dim3(256), 0, stream>>>(pa);

    WaveArgs wa;
    wa.X = X;
    wa.hs = hs;
    wa.wT = wT;
    wa.bz[0] = (const float*)d_in[2];  wa.br[0] = (const float*)d_in[4];  wa.bh[0] = (const float*)d_in[6];
    wa.bz[1] = (const float*)d_in[8];  wa.br[1] = (const float*)d_in[10]; wa.bh[1] = (const float*)d_in[12];
    wa.bz[2] = (const float*)d_in[14]; wa.br[2] = (const float*)d_in[16]; wa.bh[2] = (const float*)d_in[18];
    for (int w = 0; w < T_STEPS + 2; w++) {
        wa.w = w;
        wave_kernel<<<dim3(384), dim3(256), 0, stream>>>(wa);
    }

    HeadArgs ha;
    ha.hs = hs; ha.wT = wT; ha.y = y;
    ha.bo1 = (const float*)d_in[20];
    ha.bo2 = (const float*)d_in[22];
    ha.bo  = (const float*)d_in[24];
    head_kernel<<<dim3(5120), dim3(256), 0, stream>>>(ha);

    // zero hs[:,3] last (overwrites the wT scratch slice)
    zero_kernel<<<dim3(5120), dim3(256), 0, stream>>>(hs);
}

// Round 2
// 2941.091 us; speedup vs baseline: 1.2703x; 1.2703x over previous
//
#include <hip/hip_runtime.h>
#include <cstdint>
#include <cstddef>

// Problem constants
#define W_IMG 128
#define HW    16384            // 128*128
#define T_STEPS 20
#define BATCH 8
#define Y_SIZE 2621440         // 20*8*16384
#define HS_SLICE 1048576       // 8*8*16384  (one [t,s] slice)

__device__ __forceinline__ float sigm(float x) { return 1.0f / (1.0f + __expf(-x)); }
// tanh(x) = 1 - 2/(exp(2x)+1); safe at +/-inf, no NaN
__device__ __forceinline__ float tanh_fast(float x) { return 1.0f - 2.0f / (__expf(2.0f * x) + 1.0f); }

// ---------------------------------------------------------------------------
// Weight transpose: orig [oc][ic][3][3]  ->  wT [ic][ky][kx][oc(8)]
// wT lives in the hs[19,3] slice of d_out (written before use, zeroed last).
// ---------------------------------------------------------------------------
struct PrepArgs {
    const float* w[12];
    float* wT;
};

__global__ __launch_bounds__(256) void prep_kernel(PrepArgs a) {
    const int IC[12]  = {9, 9, 9, 16, 16, 16, 16, 16, 16, 8, 8, 8};
    const int OCc[12] = {8, 8, 8, 8, 8, 8, 8, 8, 8, 8, 8, 1};
    const int OFF[12] = {0, 648, 1296, 1944, 3096, 4248, 5400, 6552, 7704, 8856, 9432, 10008};
    const int c = blockIdx.x;           // one conv per block (grid = 12)
    const int n = IC[c] * 72;           // ic*9 taps * 8 oc (oc padded to 8)
    const float* ws = a.w[c];
    float* wd = a.wT + OFF[c];
    for (int i = threadIdx.x; i < n; i += 256) {
        const int o = i & 7;
        const int rest = i >> 3;                 // ic*9 + tap
        const int ic = rest / 9, tap = rest - ic * 9;
        float v = 0.0f;
        if (o < OCc[c]) v = ws[(o * IC[c] + ic) * 9 + tap];
        wd[i] = v;                               // dest index == (ic*9+tap)*8 + o == i
    }
}

// ---------------------------------------------------------------------------
// rz unit: one 16x16 tile. Per-ic LDS staging (bounds checked once), then
// z-conv and r-conv accumulated in registers (1 px/thread, 8 oc each).
// Epilogue: z -> zout, sigmoid(r)*h -> rhout.
// ---------------------------------------------------------------------------
template <int D, int XN>
__device__ void rz_unit(const float* __restrict__ xb, const float* __restrict__ hprev,
                        float* __restrict__ zout, float* __restrict__ rhout,
                        const float* __restrict__ wTz, const float* __restrict__ wTr,
                        const float* __restrict__ bz, const float* __restrict__ br,
                        int y0, int x0, float* buf) {
    constexpr int S = 16 + 2 * D;      // staged region side
    constexpr int IC = XN + 8;
    const int tid = threadIdx.x;
    const int ry = tid >> 4, rx = tid & 15;
    const int gy = y0 + ry, gx = x0 + rx;

    float az[8], ar[8];
#pragma unroll
    for (int o = 0; o < 8; o++) { az[o] = 0.0f; ar[o] = 0.0f; }

    const int ICe = hprev ? IC : XN;   // h == 0 at t=0: skip h channels
    for (int ic = 0; ic < ICe; ic++) {
        const float* src = (ic < XN) ? (xb + ic * HW) : (hprev + (ic - XN) * HW);
        __syncthreads();
        for (int i = tid; i < S * S; i += 256) {
            const int sy = i / S, sx = i - sy * S;
            const int yy = y0 - D + sy, xx = x0 - D + sx;
            buf[i] = (((unsigned)yy < 128u) & ((unsigned)xx < 128u)) ? src[yy * W_IMG + xx] : 0.0f;
        }
        __syncthreads();
        const float* wz = wTz + ic * 72;
        const float* wr = wTr + ic * 72;
        const int base = (ry + D) * S + (rx + D);
#pragma unroll
        for (int ky = 0; ky < 3; ky++) {
#pragma unroll
            for (int kx = 0; kx < 3; kx++) {
                const float v = buf[base + (ky - 1) * D * S + (kx - 1) * D];
                const float* w8z = wz + (ky * 3 + kx) * 8;
                const float* w8r = wr + (ky * 3 + kx) * 8;
#pragma unroll
                for (int o = 0; o < 8; o++) {
                    az[o] = fmaf(w8z[o], v, az[o]);
                    ar[o] = fmaf(w8r[o], v, ar[o]);
                }
            }
        }
    }

#pragma unroll
    for (int o = 0; o < 8; o++) {
        const float z = sigm(az[o] + bz[o]);
        const float r = sigm(ar[o] + br[o]);
        const float hv = hprev ? hprev[o * HW + gy * W_IMG + gx] : 0.0f;
        zout[o * HW + gy * W_IMG + gx] = z;
        rhout[o * HW + gy * W_IMG + gx] = r * hv;
    }
}

// ---------------------------------------------------------------------------
// h unit: candidate conv over [rh(8), x(XN)] with per-ic staging, then
// h_new = (1-z)*h + z*tanh(ah+bh) written straight to the hs slice.
// ---------------------------------------------------------------------------
template <int D, int XN>
__device__ void h_unit(const float* __restrict__ xb, const float* __restrict__ hprev,
                       const float* __restrict__ zin, const float* __restrict__ rhin,
                       float* __restrict__ outp,
                       const float* __restrict__ wTh, const float* __restrict__ bh,
                       int y0, int x0, float* buf) {
    constexpr int S = 16 + 2 * D;
    constexpr int IC = 8 + XN;         // conv input = concat(rh, x)
    const int tid = threadIdx.x;
    const int ry = tid >> 4, rx = tid & 15;
    const int gy = y0 + ry, gx = x0 + rx;

    float ah[8];
#pragma unroll
    for (int o = 0; o < 8; o++) ah[o] = 0.0f;

    for (int ic = 0; ic < IC; ic++) {
        const float* src = (ic < 8) ? (rhin + ic * HW) : (xb + (ic - 8) * HW);
        __syncthreads();
        for (int i = tid; i < S * S; i += 256) {
            const int sy = i / S, sx = i - sy * S;
            const int yy = y0 - D + sy, xx = x0 - D + sx;
            buf[i] = (((unsigned)yy < 128u) & ((unsigned)xx < 128u)) ? src[yy * W_IMG + xx] : 0.0f;
        }
        __syncthreads();
        const float* wh = wTh + ic * 72;
        const int base = (ry + D) * S + (rx + D);
#pragma unroll
        for (int ky = 0; ky < 3; ky++) {
#pragma unroll
            for (int kx = 0; kx < 3; kx++) {
                const float v = buf[base + (ky - 1) * D * S + (kx - 1) * D];
                const float* w8 = wh + (ky * 3 + kx) * 8;
#pragma unroll
                for (int o = 0; o < 8; o++) ah[o] = fmaf(w8[o], v, ah[o]);
            }
        }
    }

#pragma unroll
    for (int o = 0; o < 8; o++) {
        const int idx = o * HW + gy * W_IMG + gx;
        const float z = zin[idx];
        const float hc = tanh_fast(ah[o] + bh[o]);
        const float hv = hprev ? hprev[idx] : 0.0f;
        outp[idx] = (1.0f - z) * hv + z * hc;
    }
}

// ---------------------------------------------------------------------------
// Wave kernels: diagonal pipeline. At wave w: unit0@t=w, unit1@t=w-1,
// unit2@t=w-2 run concurrently. Grid = 3 units x 8 batch x 64 tiles = 1536.
// Scratch: z(u) in hs[t'=u, s=3], rh(u) in hs[t'=3+u, s=3] (zeroed at end).
// ---------------------------------------------------------------------------
struct WaveArgs {
    const float* X;
    float* hs;
    const float* wT;
    const float* bz[3];
    const float* br[3];
    const float* bh[3];
    int w;
};

__global__ __launch_bounds__(256) void rz_kernel(WaveArgs a) {
    __shared__ float buf[576];         // 24*24 max (D=4)
    const int unit = blockIdx.x >> 9;
    const int t = a.w - unit;
    if ((unsigned)t >= (unsigned)T_STEPS) return;
    const int b = (blockIdx.x >> 6) & 7;
    const int tile = blockIdx.x & 63;
    const int y0 = (tile >> 3) << 4, x0 = (tile & 7) << 4;
    float* hs = a.hs;
    const float* hprev = (t == 0) ? nullptr
                         : hs + (size_t)(((t - 1) * 4 + unit) * 8 + b) * (8 * HW);
    float* zout  = hs + (size_t)(((unit) * 4 + 3) * 8 + b) * (8 * HW);
    float* rhout = hs + (size_t)(((3 + unit) * 4 + 3) * 8 + b) * (8 * HW);

    if (unit == 0) {
        const float* xb = a.X + (size_t)(t * 8 + b) * HW;
        rz_unit<1, 1>(xb, hprev, zout, rhout, a.wT + 0, a.wT + 648,
                      a.bz[0], a.br[0], y0, x0, buf);
    } else if (unit == 1) {
        const float* xb = hs + (size_t)((t * 4 + 0) * 8 + b) * (8 * HW);
        rz_unit<2, 8>(xb, hprev, zout, rhout, a.wT + 1944, a.wT + 3096,
                      a.bz[1], a.br[1], y0, x0, buf);
    } else {
        const float* xb = hs + (size_t)((t * 4 + 1) * 8 + b) * (8 * HW);
        rz_unit<4, 8>(xb, hprev, zout, rhout, a.wT + 5400, a.wT + 6552,
                      a.bz[2], a.br[2], y0, x0, buf);
    }
}

__global__ __launch_bounds__(256) void h_kernel(WaveArgs a) {
    __shared__ float buf[576];
    const int unit = blockIdx.x >> 9;
    const int t = a.w - unit;
    if ((unsigned)t >= (unsigned)T_STEPS) return;
    const int b = (blockIdx.x >> 6) & 7;
    const int tile = blockIdx.x & 63;
    const int y0 = (tile >> 3) << 4, x0 = (tile & 7) << 4;
    float* hs = a.hs;
    const float* hprev = (t == 0) ? nullptr
                         : hs + (size_t)(((t - 1) * 4 + unit) * 8 + b) * (8 * HW);
    const float* zin  = hs + (size_t)(((unit) * 4 + 3) * 8 + b) * (8 * HW);
    const float* rhin = hs + (size_t)(((3 + unit) * 4 + 3) * 8 + b) * (8 * HW);
    float* outp = hs + (size_t)((t * 4 + unit) * 8 + b) * (8 * HW);

    if (unit == 0) {
        const float* xb = a.X + (size_t)(t * 8 + b) * HW;
        h_unit<1, 1>(xb, hprev, zin, rhin, outp, a.wT + 1296, a.bh[0], y0, x0, buf);
    } else if (unit == 1) {
        const float* xb = hs + (size_t)((t * 4 + 0) * 8 + b) * (8 * HW);
        h_unit<2, 8>(xb, hprev, zin, rhin, outp, a.wT + 4248, a.bh[1], y0, x0, buf);
    } else {
        const float* xb = hs + (size_t)((t * 4 + 1) * 8 + b) * (8 * HW);
        h_unit<4, 8>(xb, hprev, zin, rhin, outp, a.wT + 7704, a.bh[2], y0, x0, buf);
    }
}

// ---------------------------------------------------------------------------
// Head: y = sigmoid(conv1(relu(conv1(relu(conv2(h2)))))) fused per 32x16 tile,
// batched over all (t,b). LDS chain: h2[8][24][40] -> y1[8][20][36] ->
// y2[8][18][34] -> y[16][32].
// ---------------------------------------------------------------------------
struct HeadArgs {
    const float* hs;
    const float* wT;
    float* y;
    const float* bo1;
    const float* bo2;
    const float* bo;
};

__global__ __launch_bounds__(256) void head_kernel(HeadArgs a) {
    __shared__ float bufA[7680];   // h2 ext [8][24][40], later y2 [8][18][34]
    __shared__ float bufB[5760];   // y1 [8][20][36]
    const int tid = threadIdx.x;
    const int img = blockIdx.x >> 5;        // t*8 + b
    const int tile = blockIdx.x & 31;
    const int tx = tile & 3, tyy = tile >> 2;
    const int y0 = tyy * 16, x0 = tx * 32;
    const int t = img >> 3, b = img & 7;
    const float* h2 = a.hs + (size_t)((t * 4 + 2) * 8 + b) * (8 * HW);

    // P0: load h2 ext tile (zero-padded)
    for (int i = tid; i < 7680; i += 256) {
        const int c = i / 960, rem = i - c * 960;
        const int ey = rem / 40, ex = rem - ey * 40;
        const int gy = y0 - 4 + ey, gx = x0 - 4 + ex;
        float v = 0.0f;
        if (((unsigned)gy < 128u) && ((unsigned)gx < 128u)) v = h2[c * HW + gy * W_IMG + gx];
        bufA[i] = v;
    }
    __syncthreads();

    // P1: y1 = relu(conv d=2) on [8][20][36]
    {
        const float* wc = a.wT + 8856;
        float b1[8];
#pragma unroll
        for (int o = 0; o < 8; o++) b1[o] = a.bo1[o];
        for (int i = tid; i < 720; i += 256) {
            const int ey = i / 36, ex = i - ey * 36;
            const int gy = y0 - 2 + ey, gx = x0 - 2 + ex;
            const bool inb = ((unsigned)gy < 128u) & ((unsigned)gx < 128u);
            float acc[8];
#pragma unroll
            for (int o = 0; o < 8; o++) acc[o] = 0.0f;
            if (inb) {
                for (int ic = 0; ic < 8; ic++) {
#pragma unroll
                    for (int ky = 0; ky < 3; ky++) {
#pragma unroll
                        for (int kx = 0; kx < 3; kx++) {
                            const float v = bufA[(ic * 24 + ey + 2 + (ky - 1) * 2) * 40 + ex + 2 + (kx - 1) * 2];
                            const float* w8 = wc + ((ic * 3 + ky) * 3 + kx) * 8;
#pragma unroll
                            for (int o = 0; o < 8; o++) acc[o] = fmaf(w8[o], v, acc[o]);
                        }
                    }
                }
            }
#pragma unroll
            for (int o = 0; o < 8; o++)
                bufB[(o * 20 + ey) * 36 + ex] = inb ? fmaxf(acc[o] + b1[o], 0.0f) : 0.0f;
        }
    }
    __syncthreads();

    // P2: y2 = relu(conv d=1) on [8][18][34] -> bufA
    {
        const float* wc = a.wT + 9432;
        float b2[8];
#pragma unroll
        for (int o = 0; o < 8; o++) b2[o] = a.bo2[o];
        for (int i = tid; i < 612; i += 256) {
            const int ey = i / 34, ex = i - ey * 34;
            const int gy = y0 - 1 + ey, gx = x0 - 1 + ex;
            const bool inb = ((unsigned)gy < 128u) & ((unsigned)gx < 128u);
            float acc[8];
#pragma unroll
            for (int o = 0; o < 8; o++) acc[o] = 0.0f;
            if (inb) {
                for (int ic = 0; ic < 8; ic++) {
#pragma unroll
                    for (int ky = 0; ky < 3; ky++) {
#pragma unroll
                        for (int kx = 0; kx < 3; kx++) {
                            const float v = bufB[(ic * 20 + ey + 1 + (ky - 1)) * 36 + ex + 1 + (kx - 1)];
                            const float* w8 = wc + ((ic * 3 + ky) * 3 + kx) * 8;
#pragma unroll
                            for (int o = 0; o < 8; o++) acc[o] = fmaf(w8[o], v, acc[o]);
                        }
                    }
                }
            }
#pragma unroll
            for (int o = 0; o < 8; o++)
                bufA[(o * 18 + ey) * 34 + ex] = inb ? fmaxf(acc[o] + b2[o], 0.0f) : 0.0f;
        }
    }
    __syncthreads();

    // P3: y = sigmoid(conv d=1, 8->1) on [16][32]
    {
        const float* wc = a.wT + 10008;
        const float bo0 = a.bo[0];
        for (int i = tid; i < 512; i += 256) {
            const int ry = i >> 5, cx = i & 31;
            float acc = 0.0f;
            for (int ic = 0; ic < 8; ic++) {
#pragma unroll
                for (int ky = 0; ky < 3; ky++) {
#pragma unroll
                    for (int kx = 0; kx < 3; kx++) {
                        const float v = bufA[(ic * 18 + ry + 1 + (ky - 1)) * 34 + cx + 1 + (kx - 1)];
                        acc = fmaf(wc[((ic * 3 + ky) * 3 + kx) * 8], v, acc);
                    }
                }
            }
            a.y[(size_t)img * HW + (y0 + ry) * W_IMG + x0 + cx] = sigm(acc + bo0);
        }
    }
}

// ---------------------------------------------------------------------------
// Zero-fill hs[:,3] (including the wT + z/rh scratch slices).
// ---------------------------------------------------------------------------
__global__ __launch_bounds__(256) void zero_kernel(float* hs) {
    const size_t i = (size_t)blockIdx.x * 256 + threadIdx.x;  // < 1310720
#pragma unroll
    for (int k = 0; k < 4; k++) {
        const size_t idx = i + (size_t)k * 1310720;  // float4 index < 5242880
        const size_t t = idx >> 18;                   // / 262144
        const size_t rem = idx & 262143;
        float4* p = (float4*)(hs + (t * 4 + 3) * (size_t)HS_SLICE);
        p[rem] = make_float4(0.0f, 0.0f, 0.0f, 0.0f);
    }
}

// ---------------------------------------------------------------------------
extern "C" void kernel_launch(void* const* d_in, const int* in_sizes, int n_in,
                              void* d_out, int out_size, void* d_ws, size_t ws_size,
                              hipStream_t stream) {
    (void)in_sizes; (void)n_in; (void)d_ws; (void)ws_size; (void)out_size;

    const float* X = (const float*)d_in[0];
    float* y  = (float*)d_out;
    float* hs = (float*)d_out + Y_SIZE;
    float* wT = hs + (size_t)79 * HS_SLICE;   // hs[19,3] slice as weight scratch

    PrepArgs pa;
    pa.w[0]  = (const float*)d_in[1];   // w1z
    pa.w[1]  = (const float*)d_in[3];   // w1r
    pa.w[2]  = (const float*)d_in[5];   // w1h
    pa.w[3]  = (const float*)d_in[7];   // w2z
    pa.w[4]  = (const float*)d_in[9];   // w2r
    pa.w[5]  = (const float*)d_in[11];  // w2h
    pa.w[6]  = (const float*)d_in[13];  // w3z
    pa.w[7]  = (const float*)d_in[15];  // w3r
    pa.w[8]  = (const float*)d_in[17];  // w3h
    pa.w[9]  = (const float*)d_in[19];  // wo1
    pa.w[10] = (const float*)d_in[21];  // wo2
    pa.w[11] = (const float*)d_in[23];  // wo
    pa.wT = wT;
    prep_kernel<<<dim3(12), dim3(256), 0, stream>>>(pa);

    WaveArgs wa;
    wa.X = X;
    wa.hs = hs;
    wa.wT = wT;
    wa.bz[0] = (const float*)d_in[2];  wa.br[0] = (const float*)d_in[4];  wa.bh[0] = (const float*)d_in[6];
    wa.bz[1] = (const float*)d_in[8];  wa.br[1] = (const float*)d_in[10]; wa.bh[1] = (const float*)d_in[12];
    wa.bz[2] = (const float*)d_in[14]; wa.br[2] = (const float*)d_in[16]; wa.bh[2] = (const float*)d_in[18];
    for (int w = 0; w < T_STEPS + 2; w++) {
        wa.w = w;
        rz_kernel<<<dim3(1536), dim3(256), 0, stream>>>(wa);
        h_kernel<<<dim3(1536), dim3(256), 0, stream>>>(wa);
    }

    HeadArgs ha;
    ha.hs = hs; ha.wT = wT; ha.y = y;
    ha.bo1 = (const float*)d_in[20];
    ha.bo2 = (const float*)d_in[22];
    ha.bo  = (const float*)d_in[24];
    head_kernel<<<dim3(5120), dim3(256), 0, stream>>>(ha);

    // zero hs[:,3] last (overwrites the wT + z/rh scratch slices)
    zero_kernel<<<dim3(5120), dim3(256), 0, stream>>>(hs);
}